// Round 14
// baseline (161.097 us; speedup 1.0000x reference)
//
#include <hip/hip_runtime.h>
#include <hip/hip_bf16.h>

typedef __bf16 bf16_t;
typedef __bf16 bf16x8 __attribute__((ext_vector_type(8)));
typedef float  f32x4  __attribute__((ext_vector_type(4)));

static __device__ __forceinline__ f32x4 mfma16(bf16x8 a, bf16x8 b, f32x4 c) {
    return __builtin_amdgcn_mfma_f32_16x16x32_bf16(a, b, c, 0, 0, 0);
}

// ---------------------------------------------------------------------------
// sigma packs (R6-R13 HW-verified, UNCHANGED):
// h_phys(ht,p) = 32*(ht>>1) + 8*(p>>2) + 4*(ht&1) + (p&3). L1 MFMA output at
// lane (g,c), ht-pair (2ks,2ks+1) forms k-octet [32ks+8g..+7] of the L2
// A-fragment at the SAME lane.
// W1ef[(ht*64+l)*8+j]          = W1[128+8g+j][sig(ht,c)]
// W2f [((ks*16+ct)*64+l)*8+j]  = W2[32ks+8g+4*(j>>2)+(j&3)][ct*16+c]
// ---------------------------------------------------------------------------
__global__ void prep_pack(const float* __restrict__ W1, const float* __restrict__ W2,
                          bf16_t* __restrict__ W1ef, bf16_t* __restrict__ W2f) {
    int t = blockIdx.x * blockDim.x + threadIdx.x;
    int l = t & 63, g = l >> 4, c = l & 15;
    if (t < 1024) {
        int ht = t >> 6;
        int hcol = 32 * (ht >> 1) + 8 * (c >> 2) + 4 * (ht & 1) + (c & 3);
        #pragma unroll
        for (int j = 0; j < 8; ++j)
            W1ef[t * 8 + j] = (bf16_t)W1[(128 + 8 * g + j) * 256 + hcol];
    } else if (t < 1024 + 8192) {
        int t2 = t - 1024;
        int ks = t2 >> 10;
        int ct = (t2 >> 6) & 15;
        #pragma unroll
        for (int j = 0; j < 8; ++j) {
            int krow = 32 * ks + 8 * g + 4 * (j >> 2) + (j & 3);
            W2f[t2 * 8 + j] = (bf16_t)W2[krow * 256 + ct * 16 + c];
        }
    }
}

// ---------------------------------------------------------------------------
// Pi[b,i,h] = nodes[b,i,:] @ W1[0:128,h] + b1[h]   (f32)
// Pjb[b,j,h] = bf16( nodes[b,j,:] @ W1[160:288,h] )
// ---------------------------------------------------------------------------
__global__ __launch_bounds__(256) void prep_pij(const float* __restrict__ nodes,
                                                const float* __restrict__ W1,
                                                const float* __restrict__ b1,
                                                float* __restrict__ Pi,
                                                bf16_t* __restrict__ Pjb) {
    int b = blockIdx.x >> 3;
    int q = blockIdx.x & 7;
    int h = threadIdx.x;
    const float* nb = nodes + (b * 64 + q * 8) * 128;
    float ai[8], aj[8];
    float bias = b1[h];
    #pragma unroll
    for (int ii = 0; ii < 8; ++ii) { ai[ii] = bias; aj[ii] = 0.f; }
    for (int d = 0; d < 128; ++d) {
        float wi = W1[d * 256 + h];
        float wj = W1[(160 + d) * 256 + h];
        #pragma unroll
        for (int ii = 0; ii < 8; ++ii) {
            float s = nb[ii * 128 + d];
            ai[ii] = fmaf(s, wi, ai[ii]);
            aj[ii] = fmaf(s, wj, aj[ii]);
        }
    }
    #pragma unroll
    for (int ii = 0; ii < 8; ++ii) {
        Pi[(b * 64 + q * 8 + ii) * 256 + h] = ai[ii];
        Pjb[(b * 64 + q * 8 + ii) * 256 + h] = (bf16_t)aj[ii];
    }
}

// ---------------------------------------------------------------------------
// v14 == v13 with ONE fix: grid 512 -> 1024 blocks (8 batches each) so the
// 37 KB-LDS / 108-VGPR block actually gets 4 blocks/CU RESIDENT (R13 kept
// grid=2/CU, capping occupancy at 8 waves/CU — the counter said 21%).
// 1024 blocks x 256 thr (4 waves), 8 batches of 64 pairs, 2 barriers/batch.
// Fat-wave L2 (64 pairs x 64 cols, acc2[4][4]) halves af LDS traffic vs R8;
// laundering prevents LICM spill (R12-verified).
// ---------------------------------------------------------------------------
__global__ __launch_bounds__(256, 2) void mlp_main(
    const float* __restrict__ edges,
    const float* __restrict__ Pi, const bf16_t* __restrict__ Pjb,
    const bf16_t* __restrict__ W1ef, const bf16_t* __restrict__ W2f,
    const float* __restrict__ b2, const float* __restrict__ W3,
    const float* __restrict__ b3, float* __restrict__ out) {

    __shared__ bf16_t a1f[16384];         // 32 KB fragment-linear a1 (single)
    __shared__ bf16_t elds[2048];         // 4 KB edge fragments (single)
    __shared__ float part[4][64];         // 1 KB partial h-sums (single)

    const int p = blockIdx.x;
    const int xb = (p & 7) * 128 + (p >> 3);   // XCD swizzle (1024 % 8 == 0)
    const int tid = threadIdx.x;               // 0..255
    const int w = tid >> 6, l = tid & 63, g = l >> 4, c = l & 15;
    const int b = xb >> 3;                     // 8 blocks per batch-index b
    const f32x4 z4 = {0.f, 0.f, 0.f, 0.f};
    const float bias3 = b3[0];
    const long outbase = (long)xb * 512;       // 8 batches x 64 pairs

    // laundered loop-invariant bases (redefined each iteration -> no LICM)
    const bf16_t* W1efL = W1ef;
    const bf16_t* PjbL  = Pjb + (long)(b * 64) * 256;
    const bf16_t* W2fL  = W2f;
    const float*  b2L   = b2;
    const float*  w3L   = W3;

    // stage mapping: all 256 threads stage one 16B unit: (spt=w, sg, sc)
    const int sg = (tid >> 4) & 3, sc = tid & 15;
    const long erowbase = (long)xb * 512 + 16 * w + sc;

    f32x4 es0, es1;                        // in-flight staged edges
    {   // prologue: batch-0 edges
        const float* ep = edges + erowbase * 32 + 8 * sg;
        es0 = *(const f32x4*)ep; es1 = *(const f32x4*)(ep + 4);
        bf16x8 ev;
        #pragma unroll
        for (int j = 0; j < 4; ++j) { ev[j] = (bf16_t)es0[j]; ev[4 + j] = (bf16_t)es1[j]; }
        *(bf16x8*)&elds[tid * 8] = ev;
    }
    __syncthreads();

    for (int t = 0; t < 8; ++t) {
        // launder: blocks LICM of weight/Pj/b2/W3 loads below
        asm volatile("" : "+s"(W1efL), "+s"(PjbL), "+s"(W2fL), "+s"(b2L), "+s"(w3L));

        // issue next batch's edge loads early (land across phase A)
        if (t < 7) {
            const float* ep = edges + (erowbase + 64 * (t + 1)) * 32 + 8 * sg;
            es0 = *(const f32x4*)ep; es1 = *(const f32x4*)(ep + 4);
        }

        // deferred out-write for batch t-1 (part stable until phase B of t)
        if (t > 0 && tid < 64) {
            float s = bias3;
            #pragma unroll
            for (int cw = 0; cw < 4; ++cw) s += part[cw][tid];
            out[outbase + (t - 1) * 64 + tid] = s;
        }

        // ---------------- phase A: layer 1 (sigma; wave owns ks=2w,2w+1) -----
        {
            bf16x8 wf[4];                  // re-loaded per batch (L2$-hot)
            #pragma unroll
            for (int q = 0; q < 4; ++q)
                wf[q] = *(const bf16x8*)&W1efL[((4 * w + q) * 64 + l) * 8];
            const float* PiB = Pi + ((long)xb * 8 + t) * 256;
            f32x4 piv[2][2];
            #pragma unroll
            for (int o = 0; o < 2; ++o) {
                const float* pp = PiB + 32 * (2 * w + o) + 8 * g;
                piv[o][0] = *(const f32x4*)pp;
                piv[o][1] = *(const f32x4*)(pp + 4);
            }
            bf16x8 ebf[4];
            #pragma unroll
            for (int pt = 0; pt < 4; ++pt)
                ebf[pt] = *(const bf16x8*)&elds[(pt * 64 + l) * 8];
            #pragma unroll
            for (int pt = 0; pt < 4; ++pt) {
                #pragma unroll
                for (int o = 0; o < 2; ++o) {
                    bf16x8 pj = *(const bf16x8*)&PjbL[((long)(16 * pt + c)) * 256
                                                      + 32 * (2 * w + o) + 8 * g];
                    bf16x8 oct;
                    #pragma unroll
                    for (int z = 0; z < 2; ++z) {
                        f32x4 a = mfma16(wf[2 * o + z], ebf[pt], z4);
                        #pragma unroll
                        for (int r = 0; r < 4; ++r) {
                            float v = a[r] + piv[o][z][r] + (float)pj[4 * z + r];
                            v = v > 0.f ? v : 0.f;
                            oct[4 * z + r] = (bf16_t)v;
                        }
                    }
                    *(bf16x8*)&a1f[((pt * 8 + 2 * w + o) * 64 + l) * 8] = oct;
                }
            }
        }
        __syncthreads();                   // bar1: a1f ready, elds consumed

        // ---------------- phase B: layer 2 + 3 (wave: 64 pairs x 64 cols) ----
        {
            f32x4 acc2[4][4];              // [pt][cc], cols 64w + 16cc + 4g + r
            #pragma unroll
            for (int pt = 0; pt < 4; ++pt)
                #pragma unroll
                for (int cc = 0; cc < 4; ++cc) acc2[pt][cc] = z4;
            #pragma unroll
            for (int ks = 0; ks < 8; ++ks) {
                bf16x8 af[4];
                #pragma unroll
                for (int pt = 0; pt < 4; ++pt)
                    af[pt] = *(const bf16x8*)&a1f[((pt * 8 + ks) * 64 + l) * 8];
                #pragma unroll
                for (int cc = 0; cc < 4; ++cc) {
                    bf16x8 w2 = *(const bf16x8*)&W2fL[((ks * 16 + 4 * w + cc) * 64 + l) * 8];
                    #pragma unroll
                    for (int pt = 0; pt < 4; ++pt)
                        acc2[pt][cc] = mfma16(w2, af[pt], acc2[pt][cc]);
                }
            }

            // write-late: staged edges for batch t+1 (elds reads done at bar1)
            if (t < 7) {
                bf16x8 ev;
                #pragma unroll
                for (int j = 0; j < 4; ++j) { ev[j] = (bf16_t)es0[j]; ev[4 + j] = (bf16_t)es1[j]; }
                *(bf16x8*)&elds[tid * 8] = ev;
            }

            // L3: col = 64w + 16cc + 4g + r (in-lane), pair = 16pt + c
            #pragma unroll
            for (int pt = 0; pt < 4; ++pt) {
                float s = 0.f;
                #pragma unroll
                for (int cc = 0; cc < 4; ++cc) {
                    f32x4 b2q = *(const f32x4*)&b2L[64 * w + 16 * cc + 4 * g];
                    f32x4 w3q = *(const f32x4*)&w3L[64 * w + 16 * cc + 4 * g];
                    #pragma unroll
                    for (int r = 0; r < 4; ++r) {
                        float v = acc2[pt][cc][r] + b2q[r];
                        v = v > 0.f ? v : 0.f;
                        s = fmaf(v, w3q[r], s);
                    }
                }
                s += __shfl_xor(s, 16);    // sum the 4 g-groups
                s += __shfl_xor(s, 32);
                if (g == 0) part[w][pt * 16 + c] = s;
            }
        }
        __syncthreads();                   // bar2: part + staged elds ready
    }

    if (tid < 64) {                        // out for batch 7
        float s = bias3;
        #pragma unroll
        for (int cw = 0; cw < 4; ++cw) s += part[cw][tid];
        out[outbase + 7 * 64 + tid] = s;
    }
}

extern "C" void kernel_launch(void* const* d_in, const int* in_sizes, int n_in,
                              void* d_out, int out_size, void* d_ws, size_t ws_size,
                              hipStream_t stream) {
    const float* nodes = (const float*)d_in[0];
    const float* edges = (const float*)d_in[1];
    const float* W1    = (const float*)d_in[2];
    const float* b1    = (const float*)d_in[3];
    const float* W2    = (const float*)d_in[4];
    const float* b2    = (const float*)d_in[5];
    const float* W3    = (const float*)d_in[6];
    const float* b3    = (const float*)d_in[7];
    float* out = (float*)d_out;

    char* ws = (char*)d_ws;
    float*  Pi   = (float*)ws;                                        // 8 MB
    bf16_t* Pjb  = (bf16_t*)(ws + (size_t)8 * 1024 * 1024);           // 4 MB
    bf16_t* W2f  = (bf16_t*)(ws + (size_t)12 * 1024 * 1024);          // 128 KB
    bf16_t* W1ef = (bf16_t*)(ws + (size_t)12 * 1024 * 1024 + 131072); // 16 KB

    prep_pack<<<dim3(36), dim3(256), 0, stream>>>(W1, W2, W1ef, W2f);
    prep_pij<<<dim3(1024), dim3(256), 0, stream>>>(nodes, W1, b1, Pi, Pjb);
    mlp_main<<<dim3(1024), dim3(256), 0, stream>>>(edges, Pi, Pjb, W1ef, W2f, b2, W3, b3, out);
}

// Round 15
// 130.002 us; speedup vs baseline: 1.2392x; 1.2392x over previous
//
#include <hip/hip_runtime.h>
#include <hip/hip_bf16.h>

typedef __bf16 bf16_t;
typedef __bf16 bf16x8 __attribute__((ext_vector_type(8)));
typedef float  f32x4  __attribute__((ext_vector_type(4)));

static __device__ __forceinline__ f32x4 mfma16(bf16x8 a, bf16x8 b, f32x4 c) {
    return __builtin_amdgcn_mfma_f32_16x16x32_bf16(a, b, c, 0, 0, 0);
}

// ---------------------------------------------------------------------------
// sigma packs (R6-R14 HW-verified, UNCHANGED):
// h_phys(ht,p) = 32*(ht>>1) + 8*(p>>2) + 4*(ht&1) + (p&3). L1 MFMA output at
// lane (g,c), ht-pair (2ks,2ks+1) forms k-octet [32ks+8g..+7] of the L2
// A-fragment at the SAME lane.
// W1ef[(ht*64+l)*8+j]          = W1[128+8g+j][sig(ht,c)]
// W2f [((ks*16+ct)*64+l)*8+j]  = W2[32ks+8g+4*(j>>2)+(j&3)][ct*16+c]
// ---------------------------------------------------------------------------
__global__ void prep_pack(const float* __restrict__ W1, const float* __restrict__ W2,
                          bf16_t* __restrict__ W1ef, bf16_t* __restrict__ W2f) {
    int t = blockIdx.x * blockDim.x + threadIdx.x;
    int l = t & 63, g = l >> 4, c = l & 15;
    if (t < 1024) {
        int ht = t >> 6;
        int hcol = 32 * (ht >> 1) + 8 * (c >> 2) + 4 * (ht & 1) + (c & 3);
        #pragma unroll
        for (int j = 0; j < 8; ++j)
            W1ef[t * 8 + j] = (bf16_t)W1[(128 + 8 * g + j) * 256 + hcol];
    } else if (t < 1024 + 8192) {
        int t2 = t - 1024;
        int ks = t2 >> 10;
        int ct = (t2 >> 6) & 15;
        #pragma unroll
        for (int j = 0; j < 8; ++j) {
            int krow = 32 * ks + 8 * g + 4 * (j >> 2) + (j & 3);
            W2f[t2 * 8 + j] = (bf16_t)W2[krow * 256 + ct * 16 + c];
        }
    }
}

// ---------------------------------------------------------------------------
// Pi[b,i,h] = nodes[b,i,:] @ W1[0:128,h] + b1[h]   (f32)
// Pjb[b,j,h] = bf16( nodes[b,j,:] @ W1[160:288,h] )
// ---------------------------------------------------------------------------
__global__ __launch_bounds__(256) void prep_pij(const float* __restrict__ nodes,
                                                const float* __restrict__ W1,
                                                const float* __restrict__ b1,
                                                float* __restrict__ Pi,
                                                bf16_t* __restrict__ Pjb) {
    int b = blockIdx.x >> 3;
    int q = blockIdx.x & 7;
    int h = threadIdx.x;
    const float* nb = nodes + (b * 64 + q * 8) * 128;
    float ai[8], aj[8];
    float bias = b1[h];
    #pragma unroll
    for (int ii = 0; ii < 8; ++ii) { ai[ii] = bias; aj[ii] = 0.f; }
    for (int d = 0; d < 128; ++d) {
        float wi = W1[d * 256 + h];
        float wj = W1[(160 + d) * 256 + h];
        #pragma unroll
        for (int ii = 0; ii < 8; ++ii) {
            float s = nb[ii * 128 + d];
            ai[ii] = fmaf(s, wi, ai[ii]);
            aj[ii] = fmaf(s, wj, aj[ii]);
        }
    }
    #pragma unroll
    for (int ii = 0; ii < 8; ++ii) {
        Pi[(b * 64 + q * 8 + ii) * 256 + h] = ai[ii];
        Pjb[(b * 64 + q * 8 + ii) * 256 + h] = (bf16_t)aj[ii];
    }
}

// ---------------------------------------------------------------------------
// v15 == v8 (88 us champion structure, byte-identical layouts/barriers) with
// long-lived register hoists DEMOTED to per-batch laundered reloads, so
// combined arch-VGPR + AGPR <= ~110 < 128 -> 4 waves/SIMD -> BOTH 512-thr
// blocks/CU actually resident (R8 was register-capped at 2 waves/SIMD:
// 112 arch + 32 acc AGPR = 144 > 128).
// 512 blocks x 512 thr, 16 batches of 64 pairs, 1 barrier/batch.
// ---------------------------------------------------------------------------
__global__ __launch_bounds__(512, 2) void mlp_main(
    const float* __restrict__ edges,
    const float* __restrict__ Pi, const bf16_t* __restrict__ Pjb,
    const bf16_t* __restrict__ W1ef, const bf16_t* __restrict__ W2f,
    const float* __restrict__ b2, const float* __restrict__ W3,
    const float* __restrict__ b3, float* __restrict__ out) {

    __shared__ bf16_t a1f[2][16384];      // 2 x 32 KB fragment-linear a1
    __shared__ bf16_t elds[2][2048];      // 2 x 4 KB edge fragments (bf16)
    __shared__ float part[2][8][64];      // 2 x 2 KB partial h-sums

    const int p = blockIdx.x;
    const int xb = (p & 7) * 64 + (p >> 3);    // XCD swizzle (512 % 8 == 0)
    const int tid = threadIdx.x;
    const int w = tid >> 6, l = tid & 63, g = l >> 4, c = l & 15;
    const int b = xb >> 2;
    const f32x4 z4 = {0.f, 0.f, 0.f, 0.f};
    const float bias3 = b3[0];
    const long outbase = (long)xb * 1024;

    // laundered loop-invariant bases: redefined per iteration -> LICM cannot
    // hoist their dependent loads into long-lived registers (R12-verified)
    const bf16_t* W1efL = W1ef;
    const bf16_t* PjbL  = Pjb + (long)(b * 64) * 256;
    const bf16_t* W2fL  = W2f;
    const float*  PiL   = Pi + ((long)xb * 16) * 256;
    const float*  b2L   = b2;
    const float*  w3L   = W3;

    // stage mapping: tid<256 stages unit u=tid: (spt, sg, sc)
    const int spt = tid >> 6, sg = (tid >> 4) & 3, sc = tid & 15;
    const long erowbase = (long)xb * 1024 + 16 * spt + sc;

    f32x4 es0, es1;                        // in-flight staged edges
    if (tid < 256) {
        const float* ep = edges + erowbase * 32 + 8 * sg;
        es0 = *(const f32x4*)ep; es1 = *(const f32x4*)(ep + 4);
        bf16x8 ev;
        #pragma unroll
        for (int j = 0; j < 4; ++j) { ev[j] = (bf16_t)es0[j]; ev[4 + j] = (bf16_t)es1[j]; }
        *(bf16x8*)&elds[0][tid * 8] = ev;
    }
    __syncthreads();

    for (int t = 0; t < 16; ++t) {
        const int cur = t & 1;

        // launder (blocks LICM of every weight/Pi/Pj/b2/W3 load below)
        asm volatile("" : "+s"(W1efL), "+s"(PjbL), "+s"(W2fL),
                          "+s"(PiL), "+s"(b2L), "+s"(w3L));

        // issue next batch's edge loads early (hidden under L1+L2 of batch t)
        if (t < 15 && tid < 256) {
            const float* ep = edges + (erowbase + 64 * (t + 1)) * 32 + 8 * sg;
            es0 = *(const f32x4*)ep; es1 = *(const f32x4*)(ep + 4);
        }

        // ---------------- layer 1 (sigma-fused, reg -> LDS octets) ----------
        {
            bf16x8 wf0 = *(const bf16x8*)&W1efL[((2 * w + 0) * 64 + l) * 8];
            bf16x8 wf1 = *(const bf16x8*)&W1efL[((2 * w + 1) * 64 + l) * 8];
            const float* pp = PiL + t * 256 + 32 * w + 8 * g;
            f32x4 pva0 = *(const f32x4*)pp;
            f32x4 pva1 = *(const f32x4*)(pp + 4);
            bf16x8 ebf[4];
            #pragma unroll
            for (int pt = 0; pt < 4; ++pt)
                ebf[pt] = *(const bf16x8*)&elds[cur][(pt * 64 + l) * 8];
            #pragma unroll
            for (int pt = 0; pt < 4; ++pt) {
                bf16x8 pj = *(const bf16x8*)&PjbL[((long)(16 * pt + c)) * 256
                                                  + 32 * w + 8 * g];
                bf16x8 o;
                #pragma unroll
                for (int z = 0; z < 2; ++z) {
                    f32x4 a = mfma16(z ? wf1 : wf0, ebf[pt], z4);
                    f32x4 pv = z ? pva1 : pva0;
                    #pragma unroll
                    for (int r = 0; r < 4; ++r) {
                        float v = a[r] + pv[r] + (float)pj[4 * z + r];
                        v = v > 0.f ? v : 0.f;
                        o[4 * z + r] = (bf16_t)v;
                    }
                }
                *(bf16x8*)&a1f[cur][((pt * 8 + w) * 64 + l) * 8] = o;
            }
        }

        // write-late: staged edges for batch t+1 into the other elds buffer
        if (t < 15 && tid < 256) {
            bf16x8 ev;
            #pragma unroll
            for (int j = 0; j < 4; ++j) { ev[j] = (bf16_t)es0[j]; ev[4 + j] = (bf16_t)es1[j]; }
            *(bf16x8*)&elds[cur ^ 1][tid * 8] = ev;
        }
        __syncthreads();                   // the one barrier per batch

        // deferred out-write for batch t-1 (all waves' part complete)
        if (t > 0 && tid < 64) {
            float s = bias3;
            #pragma unroll
            for (int ww = 0; ww < 8; ++ww) s += part[cur ^ 1][ww][tid];
            out[outbase + (t - 1) * 64 + tid] = s;
        }

        // ---------------- layer 2 + layer 3 ----------------
        {
            f32x4 acc2[4][2];
            #pragma unroll
            for (int pt = 0; pt < 4; ++pt) { acc2[pt][0] = z4; acc2[pt][1] = z4; }
            #pragma unroll
            for (int ks = 0; ks < 8; ++ks) {
                bf16x8 af[4];
                #pragma unroll
                for (int pt = 0; pt < 4; ++pt)
                    af[pt] = *(const bf16x8*)&a1f[cur][((pt * 8 + ks) * 64 + l) * 8];
                #pragma unroll
                for (int cc = 0; cc < 2; ++cc) {
                    bf16x8 w2 = *(const bf16x8*)&W2fL[((ks * 16 + 2 * w + cc) * 64 + l) * 8];
                    #pragma unroll
                    for (int pt = 0; pt < 4; ++pt)
                        acc2[pt][cc] = mfma16(w2, af[pt], acc2[pt][cc]);
                }
            }
            // L3: col = 32w + 16cc + 4g + r (in-lane), pair = 16pt + c
            f32x4 b2q[2], w3q[2];
            #pragma unroll
            for (int cc = 0; cc < 2; ++cc) {
                b2q[cc] = *(const f32x4*)&b2L[32 * w + 16 * cc + 4 * g];
                w3q[cc] = *(const f32x4*)&w3L[32 * w + 16 * cc + 4 * g];
            }
            #pragma unroll
            for (int pt = 0; pt < 4; ++pt) {
                float s = 0.f;
                #pragma unroll
                for (int cc = 0; cc < 2; ++cc)
                    #pragma unroll
                    for (int r = 0; r < 4; ++r) {
                        float v = acc2[pt][cc][r] + b2q[cc][r];
                        v = v > 0.f ? v : 0.f;
                        s = fmaf(v, w3q[cc][r], s);
                    }
                s += __shfl_xor(s, 16);    // sum the 4 g-groups
                s += __shfl_xor(s, 32);
                if (g == 0) part[cur][w][pt * 16 + c] = s;
            }
        }
    }

    __syncthreads();
    if (tid < 64) {                        // out for batch 15
        float s = bias3;
        #pragma unroll
        for (int ww = 0; ww < 8; ++ww) s += part[1][ww][tid];
        out[outbase + 15 * 64 + tid] = s;
    }
}

extern "C" void kernel_launch(void* const* d_in, const int* in_sizes, int n_in,
                              void* d_out, int out_size, void* d_ws, size_t ws_size,
                              hipStream_t stream) {
    const float* nodes = (const float*)d_in[0];
    const float* edges = (const float*)d_in[1];
    const float* W1    = (const float*)d_in[2];
    const float* b1    = (const float*)d_in[3];
    const float* W2    = (const float*)d_in[4];
    const float* b2    = (const float*)d_in[5];
    const float* W3    = (const float*)d_in[6];
    const float* b3    = (const float*)d_in[7];
    float* out = (float*)d_out;

    char* ws = (char*)d_ws;
    float*  Pi   = (float*)ws;                                        // 8 MB
    bf16_t* Pjb  = (bf16_t*)(ws + (size_t)8 * 1024 * 1024);           // 4 MB
    bf16_t* W2f  = (bf16_t*)(ws + (size_t)12 * 1024 * 1024);          // 128 KB
    bf16_t* W1ef = (bf16_t*)(ws + (size_t)12 * 1024 * 1024 + 131072); // 16 KB

    prep_pack<<<dim3(36), dim3(256), 0, stream>>>(W1, W2, W1ef, W2f);
    prep_pij<<<dim3(1024), dim3(256), 0, stream>>>(nodes, W1, b1, Pi, Pjb);
    mlp_main<<<dim3(512), dim3(512), 0, stream>>>(edges, Pi, Pjb, W1ef, W2f, b2, W3, b3, out);
}